// Round 5
// baseline (349.831 us; speedup 1.0000x reference)
//
#include <hip/hip_runtime.h>
#include <math.h>

#define B_    64
#define KP1   16385                 // K+1
#define D_    128
#define NROW  500000
#define INV_T (1.0f / 0.07f)
#define MOM_  0.5f

#define BK_    (B_ * KP1)           // 1,048,640 score items per bank
#define NE4B   (NROW * (D_ / 4))    // float4 per bank
#define CHUNKSZ 2048
#define NCHUNK  245                 // ceil(500001 / 2048)
#define PADROWS (NCHUNK * CHUNKSZ)  // 501,760

#define NBLK   2048
#define NGRP   (NBLK * 8)           // 32-lane groups in main kernel

// ---- d_ws layout (bytes) ----
#define WS_COUNTS   0                                  // int[PADROWS]
#define WS_PARTIAL  (WS_COUNTS  + PADROWS * 4)         // int[PADROWS]
#define WS_BSUM     (WS_PARTIAL + PADROWS * 4)         // int[256]
#define WS_BSCAN    (WS_BSUM    + 256 * 4)             // int[256]
#define WS_RANK     (WS_BSCAN   + 256 * 4)             // int[BK_]
#define WS_ENTRIES  (WS_RANK    + BK_ * 4)             // int[BK_]

__device__ __forceinline__ float dot4(const float4 r, const float4 f) {
    return r.x * f.x + r.y * f.y + r.z * f.z + r.w * f.w;
}

// K2: histogram rows + per-item rank
__global__ __launch_bounds__(256)
void hist_kernel(const int* __restrict__ idx, int* __restrict__ counts,
                 int* __restrict__ rank) {
    for (unsigned u = blockIdx.x * 256u + threadIdx.x; u < (unsigned)BK_;
         u += gridDim.x * 256u) {
        const int r = idx[u];
        rank[u] = atomicAdd(&counts[r], 1);
    }
}

// K3a: per-2048-chunk exclusive scan of counts -> partial, chunk totals -> bsum
__global__ __launch_bounds__(256)
void scan1_kernel(const int* __restrict__ counts, int* __restrict__ partial,
                  int* __restrict__ bsum) {
    __shared__ int tsum[256];
    const int tid  = threadIdx.x;
    const int base = blockIdx.x * CHUNKSZ + tid * 8;

    int c[8], pre[8], run = 0;
    #pragma unroll
    for (int i = 0; i < 8; ++i) c[i] = counts[base + i];
    #pragma unroll
    for (int i = 0; i < 8; ++i) { pre[i] = run; run += c[i]; }

    tsum[tid] = run;
    __syncthreads();
    for (int off = 1; off < 256; off <<= 1) {
        const int add = (tid >= off) ? tsum[tid - off] : 0;
        __syncthreads();
        tsum[tid] += add;
        __syncthreads();
    }
    const int toff = tsum[tid] - run;   // exclusive
    #pragma unroll
    for (int i = 0; i < 8; ++i) partial[base + i] = toff + pre[i];
    if (tid == 255) bsum[blockIdx.x] = tsum[255];
}

// K3b: exclusive scan of the 245 chunk totals (single block)
__global__ __launch_bounds__(256)
void scan2_kernel(const int* __restrict__ bsum, int* __restrict__ bscan) {
    __shared__ int tsum[256];
    const int tid = threadIdx.x;
    const int v = (tid < NCHUNK) ? bsum[tid] : 0;
    tsum[tid] = v;
    __syncthreads();
    for (int off = 1; off < 256; off <<= 1) {
        const int add = (tid >= off) ? tsum[tid - off] : 0;
        __syncthreads();
        tsum[tid] += add;
        __syncthreads();
    }
    bscan[tid] = tsum[tid] - v;         // exclusive
}

// K4: scatter item ids into CSR entry array
__global__ __launch_bounds__(256)
void scatter_kernel(const int* __restrict__ idx, const int* __restrict__ rank,
                    const int* __restrict__ partial, const int* __restrict__ bscan,
                    int* __restrict__ entries) {
    for (unsigned u = blockIdx.x * 256u + threadIdx.x; u < (unsigned)BK_;
         u += gridDim.x * 256u) {
        const int r = idx[u];
        const int pos = partial[r] + bscan[r >> 11] + rank[u];
        entries[pos] = (int)u;
    }
}

// K5: main fused stream — copy banks + compute all scores for each row's refs.
// Group (32 lanes) per row: rows in registers, feats from L1/L2 (64KB hot set),
// butterfly reduce, two 4B scatter stores per ref. Zero random READS.
__global__ __launch_bounds__(256)
void stream_kernel(const float* __restrict__ l,
                   const float* __restrict__ ab,
                   const float* __restrict__ mem_l,
                   const float* __restrict__ mem_ab,
                   const int* __restrict__ partial,
                   const int* __restrict__ bscan,
                   const int* __restrict__ entries,
                   float* __restrict__ out,           // scores [2*BK_]
                   float* __restrict__ out_mem_l,     // bank copies
                   float* __restrict__ out_mem_ab) {
    const int glane = threadIdx.x & 31;
    const unsigned g = (blockIdx.x << 3) + (threadIdx.x >> 5);

    for (unsigned r = g; r < (unsigned)NROW; r += NGRP) {
        const float4 rl = ((const float4*)(mem_l  + (size_t)r * D_))[glane];
        const float4 ra = ((const float4*)(mem_ab + (size_t)r * D_))[glane];
        ((float4*)(out_mem_l  + (size_t)r * D_))[glane] = rl;
        ((float4*)(out_mem_ab + (size_t)r * D_))[glane] = ra;

        const int o0 = partial[r]     + bscan[r >> 11];
        const int o1 = partial[r + 1] + bscan[(r + 1) >> 11];

        for (int e = o0; e < o1; ++e) {
            const unsigned u = (unsigned)entries[e];
            const unsigned b = u / KP1;              // magic-mul div
            const float4 fl = ((const float4*)(l  + (size_t)b * D_))[glane];
            const float4 fa = ((const float4*)(ab + (size_t)b * D_))[glane];
            float sl = dot4(ra, fl);                 // out_l  = mem_ab[r].l[b]
            float sa = dot4(rl, fa);                 // out_ab = mem_l[r].ab[b]
            #pragma unroll
            for (int m = 16; m >= 1; m >>= 1) {
                sl += __shfl_xor(sl, m);
                sa += __shfl_xor(sa, m);
            }
            if (glane == 0) out[u]       = sl * INV_T;
            if (glane == 1) out[BK_ + u] = sa * INV_T;
        }
    }
}

// K6: EMA + L2-normalize the B updated rows (after stream_kernel in order)
__global__ __launch_bounds__(128)
void ema_update_kernel(const float* __restrict__ l,
                       const float* __restrict__ ab,
                       const float* __restrict__ mem_l,
                       const float* __restrict__ mem_ab,
                       const int* __restrict__ y,
                       float* __restrict__ out_mem_l,
                       float* __restrict__ out_mem_ab) {
    const int b    = blockIdx.x;
    const int wave = threadIdx.x >> 6;
    const int lane = threadIdx.x & 63;
    const int yb   = y[b];

    const float* mem  = wave ? mem_ab     : mem_l;
    const float* feat = wave ? ab         : l;
    float*       om   = wave ? out_mem_ab : out_mem_l;

    const float2 m2 = ((const float2*)(mem  + (size_t)yb * D_))[lane];
    const float2 f2 = ((const float2*)(feat + (size_t)b  * D_))[lane];

    float px = m2.x * MOM_ + f2.x * (1.0f - MOM_);
    float py = m2.y * MOM_ + f2.y * (1.0f - MOM_);
    float ss = px * px + py * py;
    #pragma unroll
    for (int m = 32; m >= 1; m >>= 1) ss += __shfl_xor(ss, m);
    const float rn = 1.0f / sqrtf(ss);

    ((float2*)(om + (size_t)yb * D_))[lane] = make_float2(px * rn, py * rn);
}

extern "C" void kernel_launch(void* const* d_in, const int* in_sizes, int n_in,
                              void* d_out, int out_size, void* d_ws, size_t ws_size,
                              hipStream_t stream) {
    const float* l      = (const float*)d_in[0];
    const float* ab     = (const float*)d_in[1];
    const float* mem_l  = (const float*)d_in[2];
    const float* mem_ab = (const float*)d_in[3];
    const int*   y      = (const int*)d_in[4];
    const int*   idx    = (const int*)d_in[5];
    float* out = (float*)d_out;

    float* out_mem_l  = out + (size_t)(2 * BK_);
    float* out_mem_ab = out_mem_l + (size_t)NROW * D_;

    char* ws = (char*)d_ws;
    int* counts  = (int*)(ws + WS_COUNTS);
    int* partial = (int*)(ws + WS_PARTIAL);
    int* bsum    = (int*)(ws + WS_BSUM);
    int* bscan   = (int*)(ws + WS_BSCAN);
    int* rank    = (int*)(ws + WS_RANK);
    int* entries = (int*)(ws + WS_ENTRIES);

    hipMemsetAsync(counts, 0, (size_t)PADROWS * 4, stream);
    hist_kernel   <<<2048, 256, 0, stream>>>(idx, counts, rank);
    scan1_kernel  <<<NCHUNK, 256, 0, stream>>>(counts, partial, bsum);
    scan2_kernel  <<<1, 256, 0, stream>>>(bsum, bscan);
    scatter_kernel<<<2048, 256, 0, stream>>>(idx, rank, partial, bscan, entries);
    stream_kernel <<<NBLK, 256, 0, stream>>>(l, ab, mem_l, mem_ab,
                                             partial, bscan, entries,
                                             out, out_mem_l, out_mem_ab);
    ema_update_kernel<<<B_, 128, 0, stream>>>(l, ab, mem_l, mem_ab, y,
                                              out_mem_l, out_mem_ab);
}